// Round 2
// baseline (687.657 us; speedup 1.0000x reference)
//
#include <hip/hip_runtime.h>
#include <hip/hip_bf16.h>
#include <stdint.h>

typedef __bf16 bf16x8 __attribute__((ext_vector_type(8)));
typedef float f32x4 __attribute__((ext_vector_type(4)));
typedef unsigned short u16x8 __attribute__((ext_vector_type(8)));

// float -> bf16 round-to-nearest-even (bit trick; inputs are finite here)
__device__ inline unsigned short f2bf_rne(float f) {
  unsigned int u = __float_as_uint(f);
  u += 0x7fffu + ((u >> 16) & 1u);
  return (unsigned short)(u >> 16);
}

// w = mu + eps * exp(0.5*lv), packed bf16. 8 elems/thread, 16B store.
__global__ __launch_bounds__(256) void prep_weight(
    const float4* __restrict__ mu, const float4* __restrict__ lv,
    const float4* __restrict__ eps, u16x8* __restrict__ wbf, int n8) {
  int i = blockIdx.x * 256 + threadIdx.x;
  if (i >= n8) return;
  float4 m0 = mu[2 * i], m1 = mu[2 * i + 1];
  float4 v0 = lv[2 * i], v1 = lv[2 * i + 1];
  float4 e0 = eps[2 * i], e1 = eps[2 * i + 1];
  u16x8 p;
  p[0] = f2bf_rne(m0.x + e0.x * __expf(0.5f * v0.x));
  p[1] = f2bf_rne(m0.y + e0.y * __expf(0.5f * v0.y));
  p[2] = f2bf_rne(m0.z + e0.z * __expf(0.5f * v0.z));
  p[3] = f2bf_rne(m0.w + e0.w * __expf(0.5f * v0.w));
  p[4] = f2bf_rne(m1.x + e1.x * __expf(0.5f * v1.x));
  p[5] = f2bf_rne(m1.y + e1.y * __expf(0.5f * v1.y));
  p[6] = f2bf_rne(m1.z + e1.z * __expf(0.5f * v1.z));
  p[7] = f2bf_rne(m1.w + e1.w * __expf(0.5f * v1.w));
  wbf[i] = p;
}

__global__ __launch_bounds__(256) void prep_x(
    const float4* __restrict__ x, u16x8* __restrict__ xbf, int n8) {
  int i = blockIdx.x * 256 + threadIdx.x;
  if (i >= n8) return;
  float4 m0 = x[2 * i], m1 = x[2 * i + 1];
  u16x8 p;
  p[0] = f2bf_rne(m0.x); p[1] = f2bf_rne(m0.y);
  p[2] = f2bf_rne(m0.z); p[3] = f2bf_rne(m0.w);
  p[4] = f2bf_rne(m1.x); p[5] = f2bf_rne(m1.y);
  p[6] = f2bf_rne(m1.z); p[7] = f2bf_rne(m1.w);
  xbf[i] = p;
}

// C[M,N] = A[M,K] * B[N,K]^T + bias(N), A/B bf16 row-major (K inner), C fp32.
// 128x128 block tile, BK=32, 4 waves 2x2, each wave 64x64 via 4x4 of 16x16x32.
// 3-buffer LDS ring + counted vmcnt (T3/T4): while computing tile t we stage
// tile t+2; tile boundary waits vmcnt(4) (tile t+1 landed; t+2's 4 loads stay
// in flight) + raw s_barrier. Loads are NEVER drained to 0 in the main loop.
// Safety: write-buf (t+2)%3 was last read in iter t-1 (sealed by its barrier);
// read-buf t%3 landing is guaranteed by prev iter's per-wave vmcnt(4)+barrier.
// LDS XOR swizzle: 16B granule c of row r holds global granule c^(r&3),
// applied on the global-address side of global_load_lds (deposit is linear);
// fragment reads XOR back -> same bank histogram as the verified BK=64 kernel
// (8 lanes per 16B column, distinct rows -> measured 0 conflicts).
#define BM 128
#define BN 128
#define BK 32
#define NBUF 3

__global__ __launch_bounds__(256, 3) void gemm_bt_bias(
    const unsigned short* __restrict__ A,   // [M][K] bf16 bits
    const unsigned short* __restrict__ B,   // [N][K] bf16 bits
    const float* __restrict__ bmu, const float* __restrict__ blv,
    const float* __restrict__ beps,
    float* __restrict__ C, int M, int N, int K) {
  __shared__ __align__(16) unsigned short As[NBUF][BM * BK];
  __shared__ __align__(16) unsigned short Bs[NBUF][BN * BK];

  const int tid  = threadIdx.x;
  const int wave = tid >> 6;
  const int lane = tid & 63;
  const int wm = wave >> 1;   // 0..1  (M direction)
  const int wn = wave & 1;    // 0..1  (N direction)

  // XCD-aware bijective swizzle (gridDim.x = 2048, divisible by 8):
  // each XCD gets 256 consecutive bids -> 8 shared A-panels in its L2.
  const int cpx = gridDim.x >> 3;
  const int bid = (blockIdx.x & 7) * cpx + (blockIdx.x >> 3);
  const int ntx = N / BN;
  const int by  = bid / ntx;
  const int bx  = bid - by * ntx;
  const int rowA0 = by * BM;
  const int rowB0 = bx * BN;

  // staging: thread t covers granule (t&3) of row (t>>2) in each 64-row round.
  // granule-in-row swizzled by row&3 on the GLOBAL side; LDS deposit linear.
  const int srow = tid >> 2;                        // 0..63
  const int scol = ((tid & 3) ^ (srow & 3)) * 8;    // swizzled elem offset
  const unsigned short* pA0 = A + (size_t)(rowA0 + srow) * K + scol;
  const unsigned short* pA1 = pA0 + (size_t)64 * K;
  const unsigned short* pB0 = B + (size_t)(rowB0 + srow) * K + scol;
  const unsigned short* pB1 = pB0 + (size_t)64 * K;
  const int ldsg = wave * 512;   // wave-uniform deposit base (elems); +lane*16B by HW

#define STAGE(kt, buf)                                                          \
  do {                                                                          \
    const size_t ko_ = (size_t)(kt) * BK;                                       \
    __builtin_amdgcn_global_load_lds(                                           \
        (const __attribute__((address_space(1))) unsigned int*)(pA0 + ko_),     \
        (__attribute__((address_space(3))) unsigned int*)&As[buf][ldsg],        \
        16, 0, 0);                                                              \
    __builtin_amdgcn_global_load_lds(                                           \
        (const __attribute__((address_space(1))) unsigned int*)(pA1 + ko_),     \
        (__attribute__((address_space(3))) unsigned int*)&As[buf][2048 + ldsg], \
        16, 0, 0);                                                              \
    __builtin_amdgcn_global_load_lds(                                           \
        (const __attribute__((address_space(1))) unsigned int*)(pB0 + ko_),     \
        (__attribute__((address_space(3))) unsigned int*)&Bs[buf][ldsg],        \
        16, 0, 0);                                                              \
    __builtin_amdgcn_global_load_lds(                                           \
        (const __attribute__((address_space(1))) unsigned int*)(pB1 + ko_),     \
        (__attribute__((address_space(3))) unsigned int*)&Bs[buf][2048 + ldsg], \
        16, 0, 0);                                                              \
  } while (0)

  f32x4 acc[4][4];
#pragma unroll
  for (int i = 0; i < 4; ++i)
#pragma unroll
    for (int j = 0; j < 4; ++j)
      acc[i][j] = (f32x4){0.f, 0.f, 0.f, 0.f};

  const int mrow = lane & 15;   // fragment row (A: m, B: n)
  const int gsel = lane >> 4;   // fragment k-granule select 0..3
  const int pgo  = (gsel ^ (mrow & 3)) * 8;          // swizzled-back elem offset
  const int aoff = (wm * 64 + mrow) * BK + pgo;
  const int boff = (wn * 64 + mrow) * BK + pgo;

  // prologue: stage tiles 0 and 1; wait until tile 0 landed (4 still flying)
  STAGE(0, 0);
  STAGE(1, 1);
  asm volatile("s_waitcnt vmcnt(4)" ::: "memory");
  __builtin_amdgcn_s_barrier();
  __builtin_amdgcn_sched_barrier(0);

  const int NT = K / BK;
  int cur = 0;
  for (int t = 0; t < NT; ++t) {
    if (t + 2 < NT) {
      int b2 = cur + 2; if (b2 >= NBUF) b2 -= NBUF;
      STAGE(t + 2, b2);
    }
    const unsigned short* as = &As[cur][0];
    const unsigned short* bs = &Bs[cur][0];
    bf16x8 af[4], bfv[4];
#pragma unroll
    for (int mi = 0; mi < 4; ++mi)
      af[mi] = *(const bf16x8*)&as[aoff + mi * (16 * BK)];
#pragma unroll
    for (int ni = 0; ni < 4; ++ni)
      bfv[ni] = *(const bf16x8*)&bs[boff + ni * (16 * BK)];
    __builtin_amdgcn_s_setprio(1);
#pragma unroll
    for (int mi = 0; mi < 4; ++mi)
#pragma unroll
      for (int ni = 0; ni < 4; ++ni)
        acc[mi][ni] = __builtin_amdgcn_mfma_f32_16x16x32_bf16(
            af[mi], bfv[ni], acc[mi][ni], 0, 0, 0);
    __builtin_amdgcn_s_setprio(0);
    if (t + 1 < NT) {
      if (t + 2 < NT) { asm volatile("s_waitcnt vmcnt(4)" ::: "memory"); }
      else            { asm volatile("s_waitcnt vmcnt(0)" ::: "memory"); }
      __builtin_amdgcn_s_barrier();
      __builtin_amdgcn_sched_barrier(0);
    }
    ++cur; if (cur >= NBUF) cur = 0;
  }

  // Epilogue: C/D layout col=lane&15, row=(lane>>4)*4+reg (m89-verified).
  const int colq = lane & 15;
  const int rq4  = (lane >> 4) * 4;
#pragma unroll
  for (int ni = 0; ni < 4; ++ni) {
    const int col = rowB0 + wn * 64 + ni * 16 + colq;
    const float bias = bmu[col] + beps[col] * __expf(0.5f * blv[col]);
#pragma unroll
    for (int mi = 0; mi < 4; ++mi) {
      const int rbase = rowA0 + wm * 64 + mi * 16 + rq4;
#pragma unroll
      for (int r = 0; r < 4; ++r)
        C[(size_t)(rbase + r) * N + col] = acc[mi][ni][r] + bias;
    }
  }
#undef STAGE
}

extern "C" void kernel_launch(void* const* d_in, const int* in_sizes, int n_in,
                              void* d_out, int out_size, void* d_ws, size_t ws_size,
                              hipStream_t stream) {
  const float* x    = (const float*)d_in[0];
  const float* wmu  = (const float*)d_in[1];
  const float* wlv  = (const float*)d_in[2];
  const float* bmu  = (const float*)d_in[3];
  const float* blv  = (const float*)d_in[4];
  const float* weps = (const float*)d_in[5];
  const float* beps = (const float*)d_in[6];
  float* out = (float*)d_out;

  const int M = 8192, N = 4096, K = 4096;

  // workspace: xbf [M*K] bf16 (64 MB) then wbf [N*K] bf16 (32 MB)
  unsigned short* xbf = (unsigned short*)d_ws;
  unsigned short* wbf = xbf + (size_t)M * K;

  const int n8w = N * K / 8;
  prep_weight<<<n8w / 256, 256, 0, stream>>>(
      (const float4*)wmu, (const float4*)wlv, (const float4*)weps,
      (u16x8*)wbf, n8w);
  const int n8x = M * K / 8;
  prep_x<<<n8x / 256, 256, 0, stream>>>((const float4*)x, (u16x8*)xbf, n8x);

  dim3 grid((M / BM) * (N / BN));  // 64*32 = 2048 blocks, 1D for XCD swizzle
  gemm_bt_bias<<<grid, 256, 0, stream>>>(xbf, wbf, bmu, blv, beps, out, M, N, K);
}

// Round 3
// 660.149 us; speedup vs baseline: 1.0417x; 1.0417x over previous
//
#include <hip/hip_runtime.h>
#include <hip/hip_bf16.h>
#include <stdint.h>

typedef __bf16 bf16x8 __attribute__((ext_vector_type(8)));
typedef float f32x4 __attribute__((ext_vector_type(4)));
typedef unsigned short u16x8 __attribute__((ext_vector_type(8)));

// float -> bf16 round-to-nearest-even (bit trick; inputs are finite here)
__device__ inline unsigned short f2bf_rne(float f) {
  unsigned int u = __float_as_uint(f);
  u += 0x7fffu + ((u >> 16) & 1u);
  return (unsigned short)(u >> 16);
}

// w = mu + eps * exp(0.5*lv), packed bf16. 8 elems/thread, 16B store.
__global__ __launch_bounds__(256) void prep_weight(
    const float4* __restrict__ mu, const float4* __restrict__ lv,
    const float4* __restrict__ eps, u16x8* __restrict__ wbf, int n8) {
  int i = blockIdx.x * 256 + threadIdx.x;
  if (i >= n8) return;
  float4 m0 = mu[2 * i], m1 = mu[2 * i + 1];
  float4 v0 = lv[2 * i], v1 = lv[2 * i + 1];
  float4 e0 = eps[2 * i], e1 = eps[2 * i + 1];
  u16x8 p;
  p[0] = f2bf_rne(m0.x + e0.x * __expf(0.5f * v0.x));
  p[1] = f2bf_rne(m0.y + e0.y * __expf(0.5f * v0.y));
  p[2] = f2bf_rne(m0.z + e0.z * __expf(0.5f * v0.z));
  p[3] = f2bf_rne(m0.w + e0.w * __expf(0.5f * v0.w));
  p[4] = f2bf_rne(m1.x + e1.x * __expf(0.5f * v1.x));
  p[5] = f2bf_rne(m1.y + e1.y * __expf(0.5f * v1.y));
  p[6] = f2bf_rne(m1.z + e1.z * __expf(0.5f * v1.z));
  p[7] = f2bf_rne(m1.w + e1.w * __expf(0.5f * v1.w));
  wbf[i] = p;
}

__global__ __launch_bounds__(256) void prep_x(
    const float4* __restrict__ x, u16x8* __restrict__ xbf, int n8) {
  int i = blockIdx.x * 256 + threadIdx.x;
  if (i >= n8) return;
  float4 m0 = x[2 * i], m1 = x[2 * i + 1];
  u16x8 p;
  p[0] = f2bf_rne(m0.x); p[1] = f2bf_rne(m0.y);
  p[2] = f2bf_rne(m0.z); p[3] = f2bf_rne(m0.w);
  p[4] = f2bf_rne(m1.x); p[5] = f2bf_rne(m1.y);
  p[6] = f2bf_rne(m1.z); p[7] = f2bf_rne(m1.w);
  xbf[i] = p;
}

// C[M,N] = A[M,K] * B[N,K]^T + bias(N), A/B bf16 row-major (K inner), C fp32.
// 128x128 block tile, BK=32, 4 waves 2x2, each wave 64x64 via 4x4 of 16x16x32.
// 3-buffer LDS ring + counted vmcnt (T3/T4): while computing tile t we stage
// tile t+2; tile boundary waits vmcnt(4) (tile t+1 landed; t+2's 4 loads stay
// in flight) + raw s_barrier. Loads are NEVER drained to 0 in the main loop.
//
// LDS XOR swizzle (R2 fix): granule g of row r holds global granule
// g ^ swz(r), swz(r) = (r&3)^((r>>2)&3). With 64B rows (4 granules), the
// quarter-wave bank model (16 lanes/cy on ds_read_b128) needs the 16 lanes of
// each gsel group to cover all 8 16B-columns of a 128B bank span twice:
// group = 4*(mrow&1) + (swz(mrow)^gsel) hits each of 8 values exactly 2x
// (enumerated) -> 2 lanes/bank = free. The R1 swz(r)=r&3 gave only 4 groups
// -> 4-way conflict, measured 3.35e7 SQ_LDS_BANK_CONFLICT.
// Grid: plain 2D dispatch (R1's XCD chunking RAISED fetch 341->550 MB; the
// default x-fastest order has better cross-XCD panel sharing).
#define BM 128
#define BN 128
#define BK 32
#define NBUF 3

__global__ __launch_bounds__(256, 3) void gemm_bt_bias(
    const unsigned short* __restrict__ A,   // [M][K] bf16 bits
    const unsigned short* __restrict__ B,   // [N][K] bf16 bits
    const float* __restrict__ bmu, const float* __restrict__ blv,
    const float* __restrict__ beps,
    float* __restrict__ C, int M, int N, int K) {
  __shared__ __align__(16) unsigned short As[NBUF][BM * BK];
  __shared__ __align__(16) unsigned short Bs[NBUF][BN * BK];

  const int tid  = threadIdx.x;
  const int wave = tid >> 6;
  const int lane = tid & 63;
  const int wm = wave >> 1;   // 0..1  (M direction)
  const int wn = wave & 1;    // 0..1  (N direction)

  const int rowA0 = blockIdx.y * BM;
  const int rowB0 = blockIdx.x * BN;

  // staging: thread t covers granule (t&3) of row (t>>2) in each 64-row round.
  // global side fetches granule (t&3)^swz(row); LDS deposit linear.
  const int srow = tid >> 2;                                        // 0..63
  const int scol = ((tid & 3) ^ (srow & 3) ^ ((srow >> 2) & 3)) * 8;
  const unsigned short* pA0 = A + (size_t)(rowA0 + srow) * K + scol;
  const unsigned short* pA1 = pA0 + (size_t)64 * K;
  const unsigned short* pB0 = B + (size_t)(rowB0 + srow) * K + scol;
  const unsigned short* pB1 = pB0 + (size_t)64 * K;
  const int ldsg = wave * 512;   // wave-uniform deposit base (elems); +lane*16B by HW

#define STAGE(kt, buf)                                                          \
  do {                                                                          \
    const size_t ko_ = (size_t)(kt) * BK;                                       \
    __builtin_amdgcn_global_load_lds(                                           \
        (const __attribute__((address_space(1))) unsigned int*)(pA0 + ko_),     \
        (__attribute__((address_space(3))) unsigned int*)&As[buf][ldsg],        \
        16, 0, 0);                                                              \
    __builtin_amdgcn_global_load_lds(                                           \
        (const __attribute__((address_space(1))) unsigned int*)(pA1 + ko_),     \
        (__attribute__((address_space(3))) unsigned int*)&As[buf][2048 + ldsg], \
        16, 0, 0);                                                              \
    __builtin_amdgcn_global_load_lds(                                           \
        (const __attribute__((address_space(1))) unsigned int*)(pB0 + ko_),     \
        (__attribute__((address_space(3))) unsigned int*)&Bs[buf][ldsg],        \
        16, 0, 0);                                                              \
    __builtin_amdgcn_global_load_lds(                                           \
        (const __attribute__((address_space(1))) unsigned int*)(pB1 + ko_),     \
        (__attribute__((address_space(3))) unsigned int*)&Bs[buf][2048 + ldsg], \
        16, 0, 0);                                                              \
  } while (0)

  f32x4 acc[4][4];
#pragma unroll
  for (int i = 0; i < 4; ++i)
#pragma unroll
    for (int j = 0; j < 4; ++j)
      acc[i][j] = (f32x4){0.f, 0.f, 0.f, 0.f};

  const int mrow = lane & 15;   // fragment row (A: m, B: n)
  const int gsel = lane >> 4;   // fragment k-granule select 0..3
  // swz(row) reduces to swz(mrow): row = 16q + mrow, bits 0..3 unaffected.
  const int pgo  = ((gsel ^ (mrow & 3) ^ ((mrow >> 2) & 3))) * 8;
  const int aoff = (wm * 64 + mrow) * BK + pgo;
  const int boff = (wn * 64 + mrow) * BK + pgo;

  // prologue: stage tiles 0 and 1; wait until tile 0 landed (4 still flying)
  STAGE(0, 0);
  STAGE(1, 1);
  asm volatile("s_waitcnt vmcnt(4)" ::: "memory");
  __builtin_amdgcn_s_barrier();
  __builtin_amdgcn_sched_barrier(0);

  const int NT = K / BK;
  int cur = 0;
  for (int t = 0; t < NT; ++t) {
    if (t + 2 < NT) {
      int b2 = cur + 2; if (b2 >= NBUF) b2 -= NBUF;
      STAGE(t + 2, b2);
    }
    const unsigned short* as = &As[cur][0];
    const unsigned short* bs = &Bs[cur][0];
    bf16x8 af[4], bfv[4];
#pragma unroll
    for (int mi = 0; mi < 4; ++mi)
      af[mi] = *(const bf16x8*)&as[aoff + mi * (16 * BK)];
#pragma unroll
    for (int ni = 0; ni < 4; ++ni)
      bfv[ni] = *(const bf16x8*)&bs[boff + ni * (16 * BK)];
    __builtin_amdgcn_s_setprio(1);
#pragma unroll
    for (int mi = 0; mi < 4; ++mi)
#pragma unroll
      for (int ni = 0; ni < 4; ++ni)
        acc[mi][ni] = __builtin_amdgcn_mfma_f32_16x16x32_bf16(
            af[mi], bfv[ni], acc[mi][ni], 0, 0, 0);
    __builtin_amdgcn_s_setprio(0);
    if (t + 1 < NT) {
      if (t + 2 < NT) { asm volatile("s_waitcnt vmcnt(4)" ::: "memory"); }
      else            { asm volatile("s_waitcnt vmcnt(0)" ::: "memory"); }
      __builtin_amdgcn_s_barrier();
      __builtin_amdgcn_sched_barrier(0);
    }
    ++cur; if (cur >= NBUF) cur = 0;
  }

  // Epilogue: C/D layout col=lane&15, row=(lane>>4)*4+reg (m89-verified).
  const int colq = lane & 15;
  const int rq4  = (lane >> 4) * 4;
#pragma unroll
  for (int ni = 0; ni < 4; ++ni) {
    const int col = rowB0 + wn * 64 + ni * 16 + colq;
    const float bias = bmu[col] + beps[col] * __expf(0.5f * blv[col]);
#pragma unroll
    for (int mi = 0; mi < 4; ++mi) {
      const int rbase = rowA0 + wm * 64 + mi * 16 + rq4;
#pragma unroll
      for (int r = 0; r < 4; ++r)
        C[(size_t)(rbase + r) * N + col] = acc[mi][ni][r] + bias;
    }
  }
#undef STAGE
}

extern "C" void kernel_launch(void* const* d_in, const int* in_sizes, int n_in,
                              void* d_out, int out_size, void* d_ws, size_t ws_size,
                              hipStream_t stream) {
  const float* x    = (const float*)d_in[0];
  const float* wmu  = (const float*)d_in[1];
  const float* wlv  = (const float*)d_in[2];
  const float* bmu  = (const float*)d_in[3];
  const float* blv  = (const float*)d_in[4];
  const float* weps = (const float*)d_in[5];
  const float* beps = (const float*)d_in[6];
  float* out = (float*)d_out;

  const int M = 8192, N = 4096, K = 4096;

  // workspace: xbf [M*K] bf16 (64 MB) then wbf [N*K] bf16 (32 MB)
  unsigned short* xbf = (unsigned short*)d_ws;
  unsigned short* wbf = xbf + (size_t)M * K;

  const int n8w = N * K / 8;
  prep_weight<<<n8w / 256, 256, 0, stream>>>(
      (const float4*)wmu, (const float4*)wlv, (const float4*)weps,
      (u16x8*)wbf, n8w);
  const int n8x = M * K / 8;
  prep_x<<<n8x / 256, 256, 0, stream>>>((const float4*)x, (u16x8*)xbf, n8x);

  dim3 grid(N / BN, M / BM);  // 32 x 64 = 2048 blocks, default dispatch order
  gemm_bt_bias<<<grid, 256, 0, stream>>>(xbf, wbf, bmu, blv, beps, out, M, N, K);
}